// Round 15
// baseline (90.791 us; speedup 1.0000x reference)
//
#include <hip/hip_runtime.h>
#include <math.h>

// Problem constants: B=1, D=H=W=24, N=13824, C=128, NUM_HEADS=4, hc=32, K3=27.
#define NTOK 13824
#define CCH 128
#define DD3 24
#define SCALE 0.17677669529663687f  // 32^-0.5
#define HSTRIDE 136                 // ushorts per halo row (272B)
#define REPS 4                      // diagnostic: true dur = shown / 4

typedef float  f32x4  __attribute__((ext_vector_type(4)));
typedef short  s16x8  __attribute__((ext_vector_type(8)));

__device__ __forceinline__ ushort bf16_rtn(float f) {
    unsigned u = __float_as_uint(f);
    unsigned r = u + 0x7fffu + ((u >> 16) & 1u);
    return (ushort)(r >> 16);
}
__device__ __forceinline__ float bf16_f32(ushort h) {
    return __uint_as_float(((unsigned)h) << 16);
}

#define BSW(n, g) ((n) * 128 + ((((g) ^ ((n) & 7))) << 3))

// ---------------------------------------------------------------------------
// prep_w (x REPS)
// ---------------------------------------------------------------------------
__global__ __launch_bounds__(256) void prep_w(
    const float* __restrict__ Wq, const float* __restrict__ Wkv,
    const float* __restrict__ Wp, ushort* __restrict__ wimg)
{
    for (int rep = 0; rep < REPS; ++rep) {
        const int i   = blockIdx.x * 256 + threadIdx.x;
        const int seg = i >> 11;
        const int r   = i & 2047;
        const int n   = r & 63;
        const int k4  = (r >> 6) * 4;
        const float* W; int ldw, scol;
        if (seg < 2)      { W = Wq;  ldw = 128; scol = seg * 64; }
        else if (seg < 6) { W = Wkv; ldw = 256; scol = (seg - 2) * 64; }
        else              { W = Wp;  ldw = 128; scol = (seg - 6) * 64; }
        ushort4 hi, lo;
        float v;
        v = W[(k4 + 0) * ldw + scol + n]; hi.x = bf16_rtn(v); lo.x = bf16_rtn(v - bf16_f32(hi.x));
        v = W[(k4 + 1) * ldw + scol + n]; hi.y = bf16_rtn(v); lo.y = bf16_rtn(v - bf16_f32(hi.y));
        v = W[(k4 + 2) * ldw + scol + n]; hi.z = bf16_rtn(v); lo.z = bf16_rtn(v - bf16_f32(hi.z));
        v = W[(k4 + 3) * ldw + scol + n]; hi.w = bf16_rtn(v); lo.w = bf16_rtn(v - bf16_f32(hi.w));
        const int g = k4 >> 3;
        const int f = seg * 16384 + BSW(n, g) + (k4 & 7);
        *(ushort4*)(wimg + f)        = hi;
        *(ushort4*)(wimg + f + 8192) = lo;
    }
}

// ---------------------------------------------------------------------------
// QKV GEMM (x REPS). grid (216, 6), block 256.
// ---------------------------------------------------------------------------
__global__ __launch_bounds__(256) void qkv_fused(
    const float* __restrict__ x, const ushort* __restrict__ wimg,
    const float* __restrict__ bq, const float* __restrict__ bkv,
    float* __restrict__ qb, ushort* __restrict__ kvb)
{
    __shared__ ushort bsh[2][8192];   // 32 KB

    const int t  = threadIdx.x;
    const int y  = blockIdx.y;
    const int wv = t >> 6, l = t & 63;
    const int lm = l & 15, lk = l >> 4;
    const int row = blockIdx.x * 64 + wv * 16 + lm;
    const int ko  = lk * 8;

    for (int rep = 0; rep < REPS; ++rep) {
        const char* wseg = (const char*)(wimg + y * 16384);
        #pragma unroll
        for (int p = 0; p < 8; ++p) {
            const int chunk = (wv * 8 + p) * 1024;
            __builtin_amdgcn_global_load_lds(
                (const __attribute__((address_space(1))) void*)(wseg + chunk + l * 16),
                (__attribute__((address_space(3))) void*)((char*)bsh + chunk),
                16, 0, 0);
        }

        s16x8 ah[4], al[4];
        #pragma unroll
        for (int kb = 0; kb < 4; ++kb) {
            const int k0 = kb * 32;
            const float4 a0 = *(const float4*)(x + row * 128 + k0 + ko);
            const float4 a1 = *(const float4*)(x + row * 128 + k0 + ko + 4);
            const float av[8] = {a0.x, a0.y, a0.z, a0.w, a1.x, a1.y, a1.z, a1.w};
            #pragma unroll
            for (int e = 0; e < 8; ++e) {
                const ushort hh = bf16_rtn(av[e]);
                ah[kb][e] = (short)hh;
                al[kb][e] = (short)bf16_rtn(av[e] - bf16_f32(hh));
            }
        }

        __syncthreads();

        f32x4 acc[4];
        #pragma unroll
        for (int nt = 0; nt < 4; ++nt)
            #pragma unroll
            for (int r = 0; r < 4; ++r) acc[nt][r] = 0.f;

        #pragma unroll
        for (int nt = 0; nt < 4; ++nt) {
            const int n = nt * 16 + lm;
            s16x8 bh[4], bl[4];
            #pragma unroll
            for (int kb = 0; kb < 4; ++kb) {
                const int g = kb * 4 + lk;
                bh[kb] = *(const s16x8*)(&bsh[0][BSW(n, g)]);
                bl[kb] = *(const s16x8*)(&bsh[1][BSW(n, g)]);
            }
            #pragma unroll
            for (int kb = 0; kb < 4; ++kb) {
                acc[nt] = __builtin_amdgcn_mfma_f32_16x16x32_bf16(ah[kb], bh[kb], acc[nt], 0, 0, 0);
                acc[nt] = __builtin_amdgcn_mfma_f32_16x16x32_bf16(ah[kb], bl[kb], acc[nt], 0, 0, 0);
                acc[nt] = __builtin_amdgcn_mfma_f32_16x16x32_bf16(al[kb], bh[kb], acc[nt], 0, 0, 0);
            }
        }

        const int orow0 = blockIdx.x * 64 + wv * 16 + lk * 4;
        #pragma unroll
        for (int nt = 0; nt < 4; ++nt) {
            const int col = y * 64 + nt * 16 + lm;
            if (col < 128) {
                const float b = bq[col];
                #pragma unroll
                for (int r = 0; r < 4; ++r)
                    qb[(orow0 + r) * 128 + col] = (acc[nt][r] + b) * SCALE;
            } else {
                const int c2 = col - 128;
                const float b = bkv[c2];
                #pragma unroll
                for (int r = 0; r < 4; ++r)
                    kvb[(orow0 + r) * 256 + c2] = bf16_rtn(acc[nt][r] + b);
            }
        }
        __syncthreads();
    }
}

// ---------------------------------------------------------------------------
// LDS-halo attention (x REPS), 8 lanes/voxel. 256 thr, grid 432.
// ---------------------------------------------------------------------------
__global__ __launch_bounds__(256) void attn3d(
    const float* __restrict__ qb, const ushort* __restrict__ kvb,
    ushort* __restrict__ aoh)
{
    __shared__ ushort sk[144 * HSTRIDE];   // 39168 B

    const int t  = threadIdx.x;
    const int b  = blockIdx.x;
    const int tw = b % 6, th = (b / 6) % 6, td = b / 36;
    const int d0 = td * 2, h0 = th * 4, w0 = tw * 4;

    const int vox = t >> 3;
    const int q8  = t & 7;
    const int ld = vox >> 4, lh = (vox >> 2) & 3, lw = vox & 3;
    const int n  = ((d0 + ld) * DD3 + (h0 + lh)) * DD3 + (w0 + lw);
    const int choff = q8 * 16;

    for (int rep = 0; rep < REPS; ++rep) {
        float qv[16];
        #pragma unroll
        for (int m = 0; m < 4; ++m) {
            const float4 qq = *(const float4*)(qb + n * 128 + choff + m * 4);
            qv[m * 4 + 0] = qq.x; qv[m * 4 + 1] = qq.y;
            qv[m * 4 + 2] = qq.z; qv[m * 4 + 3] = qq.w;
        }

        #pragma unroll
        for (int p = 0; p < 9; ++p) {
            const int e = p * 256 + t;
            const int r = e >> 4;
            const int c = e & 15;
            const int a = r / 36, bb = (r / 6) % 6, cc = r % 6;
            const int gd = d0 - 1 + a, gh = h0 - 1 + bb, gw = w0 - 1 + cc;
            int4 v = {0, 0, 0, 0};
            if ((unsigned)gd < DD3 && (unsigned)gh < DD3 && (unsigned)gw < DD3) {
                const int n2 = (gd * DD3 + gh) * DD3 + gw;
                v = *(const int4*)(kvb + n2 * 256 + c * 8);
            }
            *(int4*)(sk + r * HSTRIDE + c * 8) = v;
        }
        __syncthreads();

        const int vbase = (ld * 36 + lh * 6 + lw);
        const ushort* kvoxel = sk + vbase * HSTRIDE + choff;

        float logit[27];
        #pragma unroll
        for (int i = 0; i < 3; ++i)
            #pragma unroll
            for (int j = 0; j < 3; ++j)
                #pragma unroll
                for (int l2 = 0; l2 < 3; ++l2) {
                    const int idx = (i * 3 + j) * 3 + l2;
                    const ushort* kr = kvoxel + (i * 36 + j * 6 + l2) * HSTRIDE;
                    const int4 ka = *(const int4*)(kr);
                    const int4 kb2 = *(const int4*)(kr + 8);
                    float p = 0.f;
                    const int* kwa = (const int*)&ka;
                    const int* kwb = (const int*)&kb2;
                    #pragma unroll
                    for (int m = 0; m < 4; ++m) {
                        const unsigned u = (unsigned)kwa[m];
                        p = fmaf(qv[2 * m],     __uint_as_float(u << 16),        p);
                        p = fmaf(qv[2 * m + 1], __uint_as_float(u & 0xffff0000u), p);
                    }
                    #pragma unroll
                    for (int m = 0; m < 4; ++m) {
                        const unsigned u = (unsigned)kwb[m];
                        p = fmaf(qv[8 + 2 * m],     __uint_as_float(u << 16),        p);
                        p = fmaf(qv[8 + 2 * m + 1], __uint_as_float(u & 0xffff0000u), p);
                    }
                    p += __shfl_xor(p, 1);
                    logit[idx] = p;
                }

        float m0;
        {
            float t1[14];
            #pragma unroll
            for (int k = 0; k < 13; ++k) t1[k] = fmaxf(logit[2 * k], logit[2 * k + 1]);
            t1[13] = logit[26];
            float t2[7];
            #pragma unroll
            for (int k = 0; k < 7; ++k) t2[k] = fmaxf(t1[2 * k], t1[2 * k + 1]);
            m0 = fmaxf(fmaxf(fmaxf(t2[0], t2[1]), fmaxf(t2[2], t2[3])),
                       fmaxf(fmaxf(t2[4], t2[5]), t2[6]));
        }
        float s;
        {
            #pragma unroll
            for (int idx = 0; idx < 27; ++idx) logit[idx] = __expf(logit[idx] - m0);
            float t1[14];
            #pragma unroll
            for (int k = 0; k < 13; ++k) t1[k] = logit[2 * k] + logit[2 * k + 1];
            t1[13] = logit[26];
            float t2[7];
            #pragma unroll
            for (int k = 0; k < 7; ++k) t2[k] = t1[2 * k] + t1[2 * k + 1];
            s = ((t2[0] + t2[1]) + (t2[2] + t2[3])) + ((t2[4] + t2[5]) + t2[6]);
        }
        const float inv = 1.f / s;

        __syncthreads();

        #pragma unroll
        for (int p = 0; p < 9; ++p) {
            const int e = p * 256 + t;
            const int r = e >> 4;
            const int c = e & 15;
            const int a = r / 36, bb = (r / 6) % 6, cc = r % 6;
            const int gd = d0 - 1 + a, gh = h0 - 1 + bb, gw = w0 - 1 + cc;
            int4 v = {0, 0, 0, 0};
            if ((unsigned)gd < DD3 && (unsigned)gh < DD3 && (unsigned)gw < DD3) {
                const int n2 = (gd * DD3 + gh) * DD3 + gw;
                v = *(const int4*)(kvb + n2 * 256 + 128 + c * 8);
            }
            *(int4*)(sk + r * HSTRIDE + c * 8) = v;
        }
        __syncthreads();

        float acc[16];
        #pragma unroll
        for (int m = 0; m < 16; ++m) acc[m] = 0.f;

        #pragma unroll
        for (int i = 0; i < 3; ++i)
            #pragma unroll
            for (int j = 0; j < 3; ++j)
                #pragma unroll
                for (int l2 = 0; l2 < 3; ++l2) {
                    const int idx = (i * 3 + j) * 3 + l2;
                    const float p = logit[idx];
                    const ushort* vr = kvoxel + (i * 36 + j * 6 + l2) * HSTRIDE;
                    const int4 va = *(const int4*)(vr);
                    const int4 vb2 = *(const int4*)(vr + 8);
                    const int* vwa = (const int*)&va;
                    const int* vwb = (const int*)&vb2;
                    #pragma unroll
                    for (int m = 0; m < 4; ++m) {
                        const unsigned u = (unsigned)vwa[m];
                        acc[2 * m]     = fmaf(p, __uint_as_float(u << 16),         acc[2 * m]);
                        acc[2 * m + 1] = fmaf(p, __uint_as_float(u & 0xffff0000u), acc[2 * m + 1]);
                    }
                    #pragma unroll
                    for (int m = 0; m < 4; ++m) {
                        const unsigned u = (unsigned)vwb[m];
                        acc[8 + 2 * m]     = fmaf(p, __uint_as_float(u << 16),         acc[8 + 2 * m]);
                        acc[8 + 2 * m + 1] = fmaf(p, __uint_as_float(u & 0xffff0000u), acc[8 + 2 * m + 1]);
                    }
                }

        int pk[8];
        #pragma unroll
        for (int m = 0; m < 8; ++m) {
            const float e0 = acc[2 * m] * inv;
            const float e1 = acc[2 * m + 1] * inv;
            pk[m] = (int)bf16_rtn(e0) | ((int)bf16_rtn(e1) << 16);
        }
        int4 o0 = {pk[0], pk[1], pk[2], pk[3]};
        int4 o1 = {pk[4], pk[5], pk[6], pk[7]};
        *(int4*)(aoh + n * 128 + choff)     = o0;
        *(int4*)(aoh + n * 128 + choff + 8) = o1;
        __syncthreads();
    }
}

// ---------------------------------------------------------------------------
// Projection (x REPS). grid (216, 2), block 256.
// ---------------------------------------------------------------------------
__global__ __launch_bounds__(256) void proj_fused(
    const ushort* __restrict__ aoh, const ushort* __restrict__ wimg,
    const float* __restrict__ bp, float* __restrict__ out)
{
    __shared__ ushort bsh[2][8192];   // 32 KB

    const int t  = threadIdx.x;
    const int wv = t >> 6, l = t & 63;
    const int lm = l & 15, lk = l >> 4;
    const int row = blockIdx.x * 64 + wv * 16 + lm;
    const int ko  = lk * 8;

    for (int rep = 0; rep < REPS; ++rep) {
        const char* wseg = (const char*)(wimg + (6 + blockIdx.y) * 16384);
        #pragma unroll
        for (int p = 0; p < 8; ++p) {
            const int chunk = (wv * 8 + p) * 1024;
            __builtin_amdgcn_global_load_lds(
                (const __attribute__((address_space(1))) void*)(wseg + chunk + l * 16),
                (__attribute__((address_space(3))) void*)((char*)bsh + chunk),
                16, 0, 0);
        }

        s16x8 ah[4];
        #pragma unroll
        for (int kb = 0; kb < 4; ++kb)
            ah[kb] = *(const s16x8*)(aoh + row * 128 + kb * 32 + ko);

        __syncthreads();

        f32x4 acc[4];
        #pragma unroll
        for (int nt = 0; nt < 4; ++nt)
            #pragma unroll
            for (int r = 0; r < 4; ++r) acc[nt][r] = 0.f;

        #pragma unroll
        for (int nt = 0; nt < 4; ++nt) {
            const int n = nt * 16 + lm;
            s16x8 bh[4], bl[4];
            #pragma unroll
            for (int kb = 0; kb < 4; ++kb) {
                const int g = kb * 4 + lk;
                bh[kb] = *(const s16x8*)(&bsh[0][BSW(n, g)]);
                bl[kb] = *(const s16x8*)(&bsh[1][BSW(n, g)]);
            }
            #pragma unroll
            for (int kb = 0; kb < 4; ++kb) {
                acc[nt] = __builtin_amdgcn_mfma_f32_16x16x32_bf16(ah[kb], bh[kb], acc[nt], 0, 0, 0);
                acc[nt] = __builtin_amdgcn_mfma_f32_16x16x32_bf16(ah[kb], bl[kb], acc[nt], 0, 0, 0);
            }
        }

        const int orow0 = blockIdx.x * 64 + wv * 16 + lk * 4;
        #pragma unroll
        for (int nt = 0; nt < 4; ++nt) {
            const int col = blockIdx.y * 64 + nt * 16 + lm;
            const float b = bp[col];
            #pragma unroll
            for (int r = 0; r < 4; ++r)
                out[(orow0 + r) * 128 + col] = acc[nt][r] + b;
        }
        __syncthreads();
    }
}

extern "C" void kernel_launch(void* const* d_in, const int* in_sizes, int n_in,
                              void* d_out, int out_size, void* d_ws, size_t ws_size,
                              hipStream_t stream) {
    const float* x   = (const float*)d_in[0];
    const float* Wq  = (const float*)d_in[1];
    const float* bq  = (const float*)d_in[2];
    const float* Wkv = (const float*)d_in[3];
    const float* bkv = (const float*)d_in[4];
    const float* Wp  = (const float*)d_in[5];
    const float* bp  = (const float*)d_in[6];
    float* out = (float*)d_out;

    // workspace: qb@0, kvb@7,077,888, aoh@14,155,776, wimg@17,694,720
    char* ws = (char*)d_ws;
    float*  qb   = (float*)(ws);
    ushort* kvb  = (ushort*)(ws + 7077888);
    ushort* aoh  = (ushort*)(ws + 14155776);
    ushort* wimg = (ushort*)(ws + 17694720);

    prep_w<<<64, 256, 0, stream>>>(Wq, Wkv, Wp, wimg);
    dim3 g1(NTOK / 64, 6);
    qkv_fused<<<g1, 256, 0, stream>>>(x, wimg, bq, bkv, qb, kvb);
    attn3d<<<432, 256, 0, stream>>>(qb, kvb, aoh);
    dim3 g2(NTOK / 64, 2);
    proj_fused<<<g2, 256, 0, stream>>>(aoh, wimg, bp, out);
}